// Round 1
// baseline (15954.164 us; speedup 1.0000x reference)
//
#include <hip/hip_runtime.h>
#include <math.h>

#define NB 16
#define INW 256
#define GN 100
#define NV (GN*GN)          // 10000
#define NPROB (NB*2)        // 32
#define K_TOP 20
#define RANK_SLICES 8
#define SLICE (NV / RANK_SLICES)   // 1250

// ws byte offsets
#define OFF_RES   0               // NB*NV floats   = 640000
#define OFF_J0    640000          // GN ints        = 400
#define OFF_W     640512          // GN*4 floats    = 1600
#define OFF_SORT  643072          // NPROB*NV uint  = 1280000
#define OFF_BARS  1923072         // NPROB*NV float = 1280000
#define OFF_PART  3203072         // NPROB floats

__device__ __forceinline__ int imin(int a, int b){ return a < b ? a : b; }
__device__ __forceinline__ int imax(int a, int b){ return a > b ? a : b; }

// ---------------------------------------------------------------------------
// Kernel 0: bicubic weight table (matches jax.image.resize keys cubic a=-0.5,
// antialias=False, scale=100/256, translation=0, renormalized over valid taps)
// ---------------------------------------------------------------------------
__global__ void wg_weights(float* ws) {
  int i = threadIdx.x;
  if (i >= GN) return;
  int*   j0t = (int*)((char*)ws + OFF_J0);
  float* wt  = (float*)((char*)ws + OFF_W);
  double inv = (double)INW / (double)GN;            // 2.56
  double sf  = ((double)i + 0.5) * inv - 0.5;
  int j0 = (int)floor(sf) - 1;
  double w[4]; double s = 0.0;
  for (int k = 0; k < 4; ++k) {
    int j = j0 + k;
    double t = fabs(sf - (double)j);
    double v;
    if (t < 1.0)      v = ((1.5*t - 2.5)*t)*t + 1.0;
    else if (t < 2.0) v = ((-0.5*t + 2.5)*t - 4.0)*t + 2.0;
    else              v = 0.0;
    if (j < 0 || j >= INW) v = 0.0;   // OOB taps excluded (weight-matrix has no such row)
    w[k] = v; s += v;
  }
  for (int k = 0; k < 4; ++k) wt[i*4 + k] = (float)(w[k] / s);
  j0t[i] = j0;
}

// ---------------------------------------------------------------------------
// Kernel 1: separable bicubic resize 256x256 -> 100x100 (per batch element)
// ---------------------------------------------------------------------------
__global__ __launch_bounds__(256) void resize_k(const float* __restrict__ in, float* ws) {
  const int*   j0t = (const int*)((const char*)ws + OFF_J0);
  const float* wt  = (const float*)((const char*)ws + OFF_W);
  float* outp = (float*)((char*)ws + OFF_RES);
  int idx = blockIdx.x * 256 + threadIdx.x;
  if (idx >= NB * NV) return;
  int b = idx / NV; int rem = idx - b * NV;
  int i = rem / GN; int j = rem - i * GN;
  const float* img = in + (size_t)b * INW * INW;
  int r0 = j0t[i], c0 = j0t[j];
  float wc0 = wt[j*4+0], wc1 = wt[j*4+1], wc2 = wt[j*4+2], wc3 = wt[j*4+3];
  float acc = 0.f;
  for (int kr = 0; kr < 4; ++kr) {
    int rr = imin(imax(r0 + kr, 0), INW - 1);
    const float* row = img + rr * INW;
    int c0c = imin(imax(c0 + 0, 0), INW - 1);
    int c1c = imin(imax(c0 + 1, 0), INW - 1);
    int c2c = imin(imax(c0 + 2, 0), INW - 1);
    int c3c = imin(imax(c0 + 3, 0), INW - 1);
    float rs = wc0*row[c0c] + wc1*row[c1c] + wc2*row[c2c] + wc3*row[c3c];
    acc += wt[i*4 + kr] * rs;
  }
  outp[idx] = acc;
}

// ---------------------------------------------------------------------------
// Kernel 2: O(n^2) rank (strict total order: key desc, id asc) -> sorted ids.
// 8 slices per problem spread across CUs.
// ---------------------------------------------------------------------------
__global__ __launch_bounds__(256) void rank_k(float* ws) {
  __shared__ float sk[NV];
  int p  = blockIdx.x / RANK_SLICES;
  int sl = blockIdx.x % RANK_SLICES;
  int samp = p >> 1; int neg = p & 1;
  const float* res = (const float*)((const char*)ws + OFF_RES) + samp * NV;
  unsigned* sorted = (unsigned*)((char*)ws + OFF_SORT) + p * NV;
  float sgn = neg ? -1.f : 1.f;
  for (int i = threadIdx.x; i < NV; i += 256) sk[i] = sgn * res[i];
  __syncthreads();
  int base = sl * SLICE;
  int   own_i[5]; float own_k[5]; int own_r[5];
  #pragma unroll
  for (int k = 0; k < 5; ++k) {
    int i = base + threadIdx.x + k * 256;
    own_i[k] = i;
    bool ok = (i < base + SLICE) && (i < NV);
    own_k[k] = ok ? sk[i] : 0.f;
    own_r[k] = 0;
  }
  for (int j = 0; j < NV; ++j) {
    float kj = sk[j];
    #pragma unroll
    for (int k = 0; k < 5; ++k) {
      bool gt = (kj > own_k[k]) || (kj == own_k[k] && j < own_i[k]);
      own_r[k] += gt ? 1 : 0;
    }
  }
  #pragma unroll
  for (int k = 0; k < 5; ++k) {
    int i = own_i[k];
    if (i < base + SLICE && i < NV) sorted[own_r[k]] = (unsigned)i;
  }
}

// ---------------------------------------------------------------------------
// Kernel 3: serial union-find persistence, one WG per problem, wave0 active.
// Lane-parallel neighbor finds; lane0 does the merge (elder rule by key).
// ---------------------------------------------------------------------------
__global__ __launch_bounds__(256) void uf_k(float* ws) {
  __shared__ float sk[NV];
  __shared__ unsigned short par[NV];
  int p = blockIdx.x;
  int samp = p >> 1; int neg = p & 1;
  const float* res = (const float*)((const char*)ws + OFF_RES) + samp * NV;
  const unsigned* sorted = (const unsigned*)((const char*)ws + OFF_SORT) + p * NV;
  float* bars = (float*)((char*)ws + OFF_BARS) + p * NV;
  float sgn = neg ? -1.f : 1.f;
  for (int i = threadIdx.x; i < NV; i += 256) {
    sk[i]  = sgn * res[i];
    par[i] = (unsigned short)i;
    bars[i] = 0.f;                     // ws is poisoned; zero bar slots
  }
  __syncthreads();
  if (threadIdx.x >= 64) return;
  const int lane = threadIdx.x;
  const int deg = neg ? 4 : 6;         // complement uses 4-connectivity
  const int drs[6] = {0, 0, 1, -1, 1, -1};
  const int dcs[6] = {1, -1, 0, 0, 1, -1};
  int dr = (lane < 6) ? drs[lane] : 0;
  int dc = (lane < 6) ? dcs[lane] : 0;
  int cnt = 0;

  for (int chunk = 0; chunk < NV; chunk += 64) {
    int rem = NV - chunk; if (rem > 64) rem = 64;
    unsigned sid = 0;
    if (lane < rem) sid = sorted[chunk + lane];
    for (int t = 0; t < rem; ++t) {
      unsigned x = (unsigned)__shfl((int)sid, t, 64);
      float kx = sk[x];
      int r = (int)(x / GN), c = (int)(x % GN);
      unsigned root = 0xFFFFFFFFu;
      float rootk = 0.f;
      if (lane < deg) {
        int nr = r + dr, nc = c + dc;
        if (nr >= 0 && nr < GN && nc >= 0 && nc < GN) {
          unsigned y = (unsigned)(nr * GN + nc);
          float ky = sk[y];
          // added == earlier in (key desc, id asc) order
          bool added = (ky > kx) || (ky == kx && y < x);
          if (added) {
            unsigned cur = y;
            unsigned pp = par[cur];
            while (pp != cur) {            // path-halving find
              unsigned gp = par[pp];
              par[cur] = (unsigned short)gp;
              cur = gp;
              pp = par[cur];
            }
            root = cur;
            rootk = sk[cur];
          }
        }
      }
      unsigned rts[6]; float rks[6];
      #pragma unroll
      for (int l = 0; l < 6; ++l) {
        rts[l] = (unsigned)__shfl((int)root, l, 64);
        rks[l] = __shfl(rootk, l, 64);
      }
      if (lane == 0) {
        unsigned uniq[6]; float uk[6]; int m = 0;
        for (int l = 0; l < deg; ++l) {
          unsigned u = rts[l];
          if (u == 0xFFFFFFFFu) continue;
          bool dup = false;
          for (int q = 0; q < m; ++q) dup = dup || (uniq[q] == u);
          if (!dup) { uniq[m] = u; uk[m] = rks[l]; ++m; }
        }
        if (m == 0) {
          par[x] = (unsigned short)x;      // new peak (birth)
        } else {
          int bi = 0;
          for (int q = 1; q < m; ++q) {
            if (uk[q] > uk[bi] || (uk[q] == uk[bi] && uniq[q] < uniq[bi])) bi = q;
          }
          unsigned best = uniq[bi];
          for (int q = 0; q < m; ++q) {
            if (q != bi) {
              bars[cnt++] = uk[q] - kx;    // finite bar of the younger root
              par[uniq[q]] = (unsigned short)best;
            }
          }
          par[x] = (unsigned short)best;
        }
      }
      // make lane0's parent updates visible to all lanes before next vertex
      __asm__ volatile("s_waitcnt lgkmcnt(0)" ::: "memory");
    }
  }
}

// ---------------------------------------------------------------------------
// Kernel 4: per-problem top-20 bars, signed sum of squares -> partial[p]
// ---------------------------------------------------------------------------
__global__ __launch_bounds__(256) void topk_k(float* ws) {
  __shared__ float sb[NV];
  __shared__ float rv[256];
  __shared__ int   ri[256];
  int p = blockIdx.x;
  const float* bars = (const float*)((const char*)ws + OFF_BARS) + p * NV;
  float* part = (float*)((char*)ws + OFF_PART);
  int tid = threadIdx.x;
  for (int i = tid; i < NV; i += 256) sb[i] = bars[i];
  __syncthreads();
  float acc = 0.f;
  for (int k = 0; k < K_TOP; ++k) {
    float mv = -1.f; int mi = NV;
    for (int i = tid; i < NV; i += 256) {
      float v = sb[i];
      if (v > mv) { mv = v; mi = i; }
    }
    rv[tid] = mv; ri[tid] = mi;
    __syncthreads();
    for (int s = 128; s > 0; s >>= 1) {
      if (tid < s) {
        if (rv[tid+s] > rv[tid] || (rv[tid+s] == rv[tid] && ri[tid+s] < ri[tid])) {
          rv[tid] = rv[tid+s]; ri[tid] = ri[tid+s];
        }
      }
      __syncthreads();
    }
    if (tid == 0) {
      float best = rv[0];
      float sgnk = (k < 5) ? -1.f : 1.f;
      acc += sgnk * best * best;
      sb[ri[0]] = -2.f;                  // remove from further rounds
    }
    __syncthreads();
  }
  if (tid == 0) part[p] = acc;
}

// ---------------------------------------------------------------------------
// Kernel 5: deterministic final reduction (mean over batch)
// ---------------------------------------------------------------------------
__global__ void final_k(float* ws, float* out) {
  if (threadIdx.x == 0 && blockIdx.x == 0) {
    const float* part = (const float*)((const char*)ws + OFF_PART);
    float s = 0.f;
    for (int i = 0; i < NPROB; ++i) s += part[i];
    out[0] = s / (float)NB;
  }
}

extern "C" void kernel_launch(void* const* d_in, const int* in_sizes, int n_in,
                              void* d_out, int out_size, void* d_ws, size_t ws_size,
                              hipStream_t stream) {
  const float* in = (const float*)d_in[0];
  float* ws = (float*)d_ws;
  float* out = (float*)d_out;
  hipLaunchKernelGGL(wg_weights, dim3(1), dim3(128), 0, stream, ws);
  hipLaunchKernelGGL(resize_k, dim3((NB * NV + 255) / 256), dim3(256), 0, stream, in, ws);
  hipLaunchKernelGGL(rank_k, dim3(NPROB * RANK_SLICES), dim3(256), 0, stream, ws);
  hipLaunchKernelGGL(uf_k, dim3(NPROB), dim3(256), 0, stream, ws);
  hipLaunchKernelGGL(topk_k, dim3(NPROB), dim3(256), 0, stream, ws);
  hipLaunchKernelGGL(final_k, dim3(1), dim3(64), 0, stream, ws, out);
}

// Round 2
// 12312.175 us; speedup vs baseline: 1.2958x; 1.2958x over previous
//
#include <hip/hip_runtime.h>
#include <math.h>

#define NB 16
#define INW 256
#define GN 100
#define NV (GN*GN)          // 10000
#define NPROB (NB*2)        // 32
#define K_TOP 20
#define RANK_SLICES 8
#define SLICE (NV / RANK_SLICES)   // 1250

// ws byte offsets
#define OFF_RES   0               // NB*NV floats   = 640000
#define OFF_J0    640000          // GN ints        = 400
#define OFF_W     640512          // GN*4 floats    = 1600
#define OFF_SORT  643072          // NPROB*NV uint  = 1280000
#define OFF_BARS  1923072         // NPROB*NV float = 1280000
#define OFF_PART  3203072         // NPROB floats

__device__ __forceinline__ int imin(int a, int b){ return a < b ? a : b; }
__device__ __forceinline__ int imax(int a, int b){ return a > b ? a : b; }

// ---------------------------------------------------------------------------
// Kernel 0: bicubic weight table (jax.image.resize keys cubic a=-0.5,
// antialias=False, renormalized over valid taps)
// ---------------------------------------------------------------------------
__global__ void wg_weights(float* ws) {
  int i = threadIdx.x;
  if (i >= GN) return;
  int*   j0t = (int*)((char*)ws + OFF_J0);
  float* wt  = (float*)((char*)ws + OFF_W);
  double inv = (double)INW / (double)GN;            // 2.56
  double sf  = ((double)i + 0.5) * inv - 0.5;
  int j0 = (int)floor(sf) - 1;
  double w[4]; double s = 0.0;
  for (int k = 0; k < 4; ++k) {
    int j = j0 + k;
    double t = fabs(sf - (double)j);
    double v;
    if (t < 1.0)      v = ((1.5*t - 2.5)*t)*t + 1.0;
    else if (t < 2.0) v = ((-0.5*t + 2.5)*t - 4.0)*t + 2.0;
    else              v = 0.0;
    if (j < 0 || j >= INW) v = 0.0;
    w[k] = v; s += v;
  }
  for (int k = 0; k < 4; ++k) wt[i*4 + k] = (float)(w[k] / s);
  j0t[i] = j0;
}

// ---------------------------------------------------------------------------
// Kernel 1: separable bicubic resize 256x256 -> 100x100
// ---------------------------------------------------------------------------
__global__ __launch_bounds__(256) void resize_k(const float* __restrict__ in, float* ws) {
  const int*   j0t = (const int*)((const char*)ws + OFF_J0);
  const float* wt  = (const float*)((const char*)ws + OFF_W);
  float* outp = (float*)((char*)ws + OFF_RES);
  int idx = blockIdx.x * 256 + threadIdx.x;
  if (idx >= NB * NV) return;
  int b = idx / NV; int rem = idx - b * NV;
  int i = rem / GN; int j = rem - i * GN;
  const float* img = in + (size_t)b * INW * INW;
  int r0 = j0t[i], c0 = j0t[j];
  float wc0 = wt[j*4+0], wc1 = wt[j*4+1], wc2 = wt[j*4+2], wc3 = wt[j*4+3];
  float acc = 0.f;
  for (int kr = 0; kr < 4; ++kr) {
    int rr = imin(imax(r0 + kr, 0), INW - 1);
    const float* row = img + rr * INW;
    int c0c = imin(imax(c0 + 0, 0), INW - 1);
    int c1c = imin(imax(c0 + 1, 0), INW - 1);
    int c2c = imin(imax(c0 + 2, 0), INW - 1);
    int c3c = imin(imax(c0 + 3, 0), INW - 1);
    float rs = wc0*row[c0c] + wc1*row[c1c] + wc2*row[c2c] + wc3*row[c3c];
    acc += wt[i*4 + kr] * rs;
  }
  outp[idx] = acc;
}

// ---------------------------------------------------------------------------
// Kernel 2: O(n^2) rank (key desc, id asc) -> sorted ids. float4 LDS scan.
// ---------------------------------------------------------------------------
__global__ __launch_bounds__(256) void rank_k(float* ws) {
  __shared__ __align__(16) float sk[NV];
  int p  = blockIdx.x / RANK_SLICES;
  int sl = blockIdx.x % RANK_SLICES;
  int samp = p >> 1; int neg = p & 1;
  const float* res = (const float*)((const char*)ws + OFF_RES) + samp * NV;
  unsigned* sorted = (unsigned*)((char*)ws + OFF_SORT) + (size_t)p * NV;
  float sgn = neg ? -1.f : 1.f;
  for (int i = threadIdx.x; i < NV; i += 256) sk[i] = sgn * res[i];
  __syncthreads();
  int base = sl * SLICE;
  int   own_i[5]; float own_k[5]; int own_r[5];
  #pragma unroll
  for (int k = 0; k < 5; ++k) {
    int i = base + threadIdx.x + k * 256;
    own_i[k] = i;
    bool ok = (i < base + SLICE) && (i < NV);
    own_k[k] = ok ? sk[i] : 0.f;
    own_r[k] = 0;
  }
  const float4* sk4 = (const float4*)sk;
  for (int j4 = 0; j4 < NV/4; ++j4) {
    float4 kv = sk4[j4];
    int jb = j4 * 4;
    #pragma unroll
    for (int q = 0; q < 4; ++q) {
      float kj = (q==0) ? kv.x : (q==1) ? kv.y : (q==2) ? kv.z : kv.w;
      int j = jb + q;
      #pragma unroll
      for (int k = 0; k < 5; ++k) {
        bool gt = (kj > own_k[k]) || (kj == own_k[k] && j < own_i[k]);
        own_r[k] += gt ? 1 : 0;
      }
    }
  }
  #pragma unroll
  for (int k = 0; k < 5; ++k) {
    int i = own_i[k];
    if (i < base + SLICE && i < NV) sorted[own_r[k]] = (unsigned)i;
  }
}

// ---------------------------------------------------------------------------
// Kernel 3: union-find persistence. One WG per problem.
// Wave-parallel record precompute (static data) + lane-0 serial merges with
// batched LDS pointer chases. Zero cross-lane shuffles in the serial path.
// ---------------------------------------------------------------------------
__global__ __launch_bounds__(256) void uf_k(float* ws) {
  __shared__ __align__(16) float sk[NV];                 // 40000 B
  __shared__ unsigned short par[NV];                     // 20000 B
  __shared__ __align__(16) uint4 staging[65*3];          // 3120 B
  int p = blockIdx.x;
  int samp = p >> 1; int neg = p & 1;
  const float* res = (const float*)((const char*)ws + OFF_RES) + samp * NV;
  const unsigned* sorted = (const unsigned*)((const char*)ws + OFF_SORT) + (size_t)p * NV;
  float* bars = (float*)((char*)ws + OFF_BARS) + (size_t)p * NV;
  float sgn = neg ? -1.f : 1.f;
  for (int i = threadIdx.x; i < NV; i += 256) {
    sk[i]  = sgn * res[i];
    par[i] = (unsigned short)i;
    bars[i] = 0.f;
  }
  __syncthreads();
  if (threadIdx.x >= 64) return;
  const int lane = threadIdx.x;
  const int deg = neg ? 4 : 6;
  const int offs[6] = {1, -1, GN, -GN, GN+1, -GN-1};
  int nb = 0;

  for (int chunk = 0; chunk < NV; chunk += 64) {
    int rem = NV - chunk; if (rem > 64) rem = 64;
    // ---- parallel precompute of per-vertex records (uses only static sk) ----
    {
      int idx = chunk + lane;
      unsigned x = 0; unsigned mask = 0; float kx = 0.f;
      float kk[6] = {0.f,0.f,0.f,0.f,0.f,0.f};
      if (idx < NV) {
        x = sorted[idx];
        kx = sk[x];
        int r = (int)(x / GN), c = (int)(x % GN);
        bool inb0 = (c < GN-1), inb1 = (c > 0), inb2 = (r < GN-1), inb3 = (r > 0);
        bool inb[6] = { inb0, inb1, inb2, inb3, inb2 && inb0, inb3 && inb1 };
        #pragma unroll
        for (int d = 0; d < 6; ++d) {
          if (d < deg && inb[d]) {
            unsigned y = (unsigned)((int)x + offs[d]);
            float ky = sk[y];
            // added == earlier in (key desc, id asc) processing order (static!)
            bool added = (ky > kx) || (ky == kx && y < x);
            if (added) { mask |= (1u << d); kk[d] = ky; }
          }
        }
      }
      uint4 a, b, c4;
      a.x = x; a.y = mask; a.z = __float_as_uint(kx); a.w = 0;
      b.x = __float_as_uint(kk[0]); b.y = __float_as_uint(kk[1]);
      b.z = __float_as_uint(kk[2]); b.w = __float_as_uint(kk[3]);
      c4.x = __float_as_uint(kk[4]); c4.y = __float_as_uint(kk[5]); c4.z = 0; c4.w = 0;
      staging[lane*3+0] = a; staging[lane*3+1] = b; staging[lane*3+2] = c4;
    }
    __builtin_amdgcn_wave_barrier();
    __asm__ volatile("" ::: "memory");     // DS ops within a wave complete in order
    // ---- serial union-find on lane 0 ----
    if (lane == 0) {
      uint4 ra = staging[0], rb = staging[1], rc = staging[2];
      for (int t = 0; t < rem; ++t) {
        // prefetch next record (slot rem<=64 exists; garbage never consumed)
        int nt3 = (t + 1) * 3;
        uint4 na = staging[nt3 + 0], nbb = staging[nt3 + 1], ncc = staging[nt3 + 2];
        unsigned x = ra.x, mask = ra.y;
        float kx = __uint_as_float(ra.z);
        float k[6];
        k[0]=__uint_as_float(rb.x); k[1]=__uint_as_float(rb.y);
        k[2]=__uint_as_float(rb.z); k[3]=__uint_as_float(rb.w);
        k[4]=__uint_as_float(rc.x); k[5]=__uint_as_float(rc.y);
        if (mask) {
          unsigned cur[6], st[6];
          #pragma unroll
          for (int d = 0; d < 6; ++d) {
            bool a = (mask >> d) & 1u;
            st[d] = a ? (unsigned)((int)x + offs[d]) : x;   // inactive slots park at x (par[x]==x)
            cur[d] = st[d];
          }
          // batched pointer chase with path halving (all writes semantics-preserving)
          while (1) {
            unsigned nx[6];
            #pragma unroll
            for (int d = 0; d < 6; ++d) nx[d] = par[cur[d]];
            bool done = true;
            #pragma unroll
            for (int d = 0; d < 6; ++d) done &= (nx[d] == cur[d]);
            if (done) break;
            unsigned gp[6];
            #pragma unroll
            for (int d = 0; d < 6; ++d) gp[d] = par[nx[d]];
            #pragma unroll
            for (int d = 0; d < 6; ++d) par[cur[d]] = (unsigned short)gp[d];
            bool done2 = true;
            #pragma unroll
            for (int d = 0; d < 6; ++d) done2 &= (gp[d] == nx[d]);
            #pragma unroll
            for (int d = 0; d < 6; ++d) cur[d] = gp[d];
            if (done2) break;
          }
          bool movedany = false;
          #pragma unroll
          for (int d = 0; d < 6; ++d) movedany |= (cur[d] != st[d]);
          float rk[6];
          if (movedany) {
            #pragma unroll
            for (int d = 0; d < 6; ++d) rk[d] = sk[cur[d]];   // batched, one wait
          } else {
            #pragma unroll
            for (int d = 0; d < 6; ++d) rk[d] = k[d];         // no LDS read at all
          }
          // dedup roots
          bool uq[6];
          #pragma unroll
          for (int d = 0; d < 6; ++d) {
            uq[d] = (mask >> d) & 1u;
            #pragma unroll
            for (int e = 0; e < 6; ++e) {
              if (e < d) {
                bool ae = (mask >> e) & 1u;
                if (ae && cur[e] == cur[d]) uq[d] = false;
              }
            }
          }
          // elder rule: survivor = (key desc, id asc)-max root
          float bk = 0.f; unsigned best = 0xFFFFFFFFu;
          #pragma unroll
          for (int d = 0; d < 6; ++d) {
            if (uq[d]) {
              bool better = (best == 0xFFFFFFFFu) || (rk[d] > bk) ||
                            (rk[d] == bk && cur[d] < best);
              if (better) { bk = rk[d]; best = cur[d]; }
            }
          }
          #pragma unroll
          for (int d = 0; d < 6; ++d) {
            if (uq[d] && cur[d] != best) {
              bars[nb++] = rk[d] - kx;            // finite bar of defeated root
              par[cur[d]] = (unsigned short)best;
            }
          }
          par[x] = (unsigned short)best;
        }
        ra = na; rb = nbb; rc = ncc;
      }
    }
    __builtin_amdgcn_wave_barrier();
    __asm__ volatile("" ::: "memory");
  }
}

// ---------------------------------------------------------------------------
// Kernel 4: per-problem top-20 bars, signed sum of squares -> partial[p]
// ---------------------------------------------------------------------------
__global__ __launch_bounds__(256) void topk_k(float* ws) {
  __shared__ float sb[NV];
  __shared__ float rv[256];
  __shared__ int   ri[256];
  int p = blockIdx.x;
  const float* bars = (const float*)((const char*)ws + OFF_BARS) + (size_t)p * NV;
  float* part = (float*)((char*)ws + OFF_PART);
  int tid = threadIdx.x;
  for (int i = tid; i < NV; i += 256) sb[i] = bars[i];
  __syncthreads();
  float acc = 0.f;
  for (int k = 0; k < K_TOP; ++k) {
    float mv = -1.f; int mi = NV;
    for (int i = tid; i < NV; i += 256) {
      float v = sb[i];
      if (v > mv) { mv = v; mi = i; }
    }
    rv[tid] = mv; ri[tid] = mi;
    __syncthreads();
    for (int s = 128; s > 0; s >>= 1) {
      if (tid < s) {
        if (rv[tid+s] > rv[tid] || (rv[tid+s] == rv[tid] && ri[tid+s] < ri[tid])) {
          rv[tid] = rv[tid+s]; ri[tid] = ri[tid+s];
        }
      }
      __syncthreads();
    }
    if (tid == 0) {
      float best = rv[0];
      float sgnk = (k < 5) ? -1.f : 1.f;
      acc += sgnk * best * best;
      sb[ri[0]] = -2.f;
    }
    __syncthreads();
  }
  if (tid == 0) part[p] = acc;
}

// ---------------------------------------------------------------------------
// Kernel 5: deterministic final reduction (mean over batch)
// ---------------------------------------------------------------------------
__global__ void final_k(float* ws, float* out) {
  if (threadIdx.x == 0 && blockIdx.x == 0) {
    const float* part = (const float*)((const char*)ws + OFF_PART);
    float s = 0.f;
    for (int i = 0; i < NPROB; ++i) s += part[i];
    out[0] = s / (float)NB;
  }
}

extern "C" void kernel_launch(void* const* d_in, const int* in_sizes, int n_in,
                              void* d_out, int out_size, void* d_ws, size_t ws_size,
                              hipStream_t stream) {
  const float* in = (const float*)d_in[0];
  float* ws = (float*)d_ws;
  float* out = (float*)d_out;
  hipLaunchKernelGGL(wg_weights, dim3(1), dim3(128), 0, stream, ws);
  hipLaunchKernelGGL(resize_k, dim3((NB * NV + 255) / 256), dim3(256), 0, stream, in, ws);
  hipLaunchKernelGGL(rank_k, dim3(NPROB * RANK_SLICES), dim3(256), 0, stream, ws);
  hipLaunchKernelGGL(uf_k, dim3(NPROB), dim3(256), 0, stream, ws);
  hipLaunchKernelGGL(topk_k, dim3(NPROB), dim3(256), 0, stream, ws);
  hipLaunchKernelGGL(final_k, dim3(1), dim3(64), 0, stream, ws, out);
}

// Round 3
// 3008.829 us; speedup vs baseline: 5.3025x; 4.0920x over previous
//
#include <hip/hip_runtime.h>
#include <math.h>

#define NB 16
#define INW 256
#define GN 100
#define NV (GN*GN)          // 10000
#define NPROB (NB*2)        // 32
#define K_TOP 20
#define HSZ 8192
#define HMASK (HSZ-1)
#define EMPTYK 0xFFFFFFFFu

// ws byte offsets
#define OFF_RES   0               // NB*NV floats   = 640000
#define OFF_J0    640000          // GN ints
#define OFF_W     641024          // GN*4 floats
#define OFF_BARS  643072          // NPROB*NV float = 1280000
#define OFF_PART  1923072         // NPROB floats

__device__ __forceinline__ int imin(int a, int b){ return a < b ? a : b; }
__device__ __forceinline__ int imax(int a, int b){ return a > b ? a : b; }

// monotone float<->uint order map
__device__ __forceinline__ unsigned mono32(float f){
  unsigned b = __float_as_uint(f);
  return (b & 0x80000000u) ? ~b : (b | 0x80000000u);
}
__device__ __forceinline__ float unmono(unsigned m){
  unsigned b = (m & 0x80000000u) ? (m ^ 0x80000000u) : ~m;
  return __uint_as_float(b);
}

// ---------------------------------------------------------------------------
// Kernel 0: bicubic weight table (jax.image.resize keys cubic a=-0.5)
// ---------------------------------------------------------------------------
__global__ void wg_weights(float* ws) {
  int i = threadIdx.x;
  if (i >= GN) return;
  int*   j0t = (int*)((char*)ws + OFF_J0);
  float* wt  = (float*)((char*)ws + OFF_W);
  double inv = (double)INW / (double)GN;
  double sf  = ((double)i + 0.5) * inv - 0.5;
  int j0 = (int)floor(sf) - 1;
  double w[4]; double s = 0.0;
  for (int k = 0; k < 4; ++k) {
    int j = j0 + k;
    double t = fabs(sf - (double)j);
    double v;
    if (t < 1.0)      v = ((1.5*t - 2.5)*t)*t + 1.0;
    else if (t < 2.0) v = ((-0.5*t + 2.5)*t - 4.0)*t + 2.0;
    else              v = 0.0;
    if (j < 0 || j >= INW) v = 0.0;
    w[k] = v; s += v;
  }
  for (int k = 0; k < 4; ++k) wt[i*4 + k] = (float)(w[k] / s);
  j0t[i] = j0;
}

// ---------------------------------------------------------------------------
// Kernel 1: separable bicubic resize 256x256 -> 100x100
// ---------------------------------------------------------------------------
__global__ __launch_bounds__(256) void resize_k(const float* __restrict__ in, float* ws) {
  const int*   j0t = (const int*)((const char*)ws + OFF_J0);
  const float* wt  = (const float*)((const char*)ws + OFF_W);
  float* outp = (float*)((char*)ws + OFF_RES);
  int idx = blockIdx.x * 256 + threadIdx.x;
  if (idx >= NB * NV) return;
  int b = idx / NV; int rem = idx - b * NV;
  int i = rem / GN; int j = rem - i * GN;
  const float* img = in + (size_t)b * INW * INW;
  int r0 = j0t[i], c0 = j0t[j];
  float wc0 = wt[j*4+0], wc1 = wt[j*4+1], wc2 = wt[j*4+2], wc3 = wt[j*4+3];
  float acc = 0.f;
  for (int kr = 0; kr < 4; ++kr) {
    int rr = imin(imax(r0 + kr, 0), INW - 1);
    const float* row = img + rr * INW;
    int c0c = imin(imax(c0 + 0, 0), INW - 1);
    int c1c = imin(imax(c0 + 1, 0), INW - 1);
    int c2c = imin(imax(c0 + 2, 0), INW - 1);
    int c3c = imin(imax(c0 + 3, 0), INW - 1);
    float rs = wc0*row[c0c] + wc1*row[c1c] + wc2*row[c2c] + wc3*row[c3c];
    acc += wt[i*4 + kr] * rs;
  }
  outp[idx] = acc;
}

// ---------------------------------------------------------------------------
// Kernel 2: region-contracted persistence. One WG (256 thr) per problem.
//  P1: steepest-earlier-neighbor forest + pointer-jump watershed labels
//  P2: boundary-edge hashing -> per-region-pair earliest event (LDS table)
//  P3: bitonic sort of super-edges by event (descending = chronological)
//  P4: serial elder-rule Kruskal over ~few-k super-edges (lane 0)
// ---------------------------------------------------------------------------
__global__ __launch_bounds__(256) void region_k(float* ws) {
  __shared__ unsigned long long hval[HSZ];   // event ords (sort key)
  __shared__ unsigned sm[NV];                // mono keys
  __shared__ unsigned hkey[HSZ];             // pair ids (payload)
  __shared__ unsigned short lab[NV];         // labels, then UF parent
  int p = blockIdx.x, samp = p >> 1, neg = p & 1, tid = threadIdx.x;
  const float* res = (const float*)((const char*)ws + OFF_RES) + samp * NV;
  float* bars = (float*)((char*)ws + OFF_BARS) + (size_t)p * NV;
  float sgn = neg ? -1.f : 1.f;

  for (int i = tid; i < NV; i += 256) { sm[i] = mono32(sgn * res[i]); bars[i] = 0.f; }
  for (int s = tid; s < HSZ; s += 256) { hkey[s] = EMPTYK; hval[s] = 0ull; }
  __syncthreads();

  // ---- P1: steepest earlier neighbor (max ord among neighbors, incl self) ----
  const int nd = neg ? 4 : 6;
  for (int v = tid; v < NV; v += 256) {
    int r = v / GN, c = v - r * GN;
    unsigned long long best = ((unsigned long long)sm[v] << 32) | (unsigned)~(unsigned)v;
    unsigned bi = (unsigned)v;
    bool cb[6] = { c < GN-1, c > 0, r < GN-1, r > 0,
                   (r < GN-1) && (c < GN-1), (r > 0) && (c > 0) };
    int  off[6] = { 1, -1, GN, -GN, GN+1, -(GN+1) };
    #pragma unroll
    for (int d = 0; d < 6; ++d) {
      if (d < nd && cb[d]) {
        unsigned y = (unsigned)(v + off[d]);
        unsigned long long o = ((unsigned long long)sm[y] << 32) | (unsigned)~y;
        if (o > best) { best = o; bi = y; }
      }
    }
    lab[v] = (unsigned short)bi;
  }
  __syncthreads();
  // pointer jumping: 14 rounds covers depth 16384 >= any chain
  for (int rd = 0; rd < 14; ++rd) {
    for (int v = tid; v < NV; v += 256) lab[v] = lab[lab[v]];
    __syncthreads();
  }

  // ---- P2: boundary edges -> hash (pair -> max event ord) ----
  for (int v = tid; v < NV; v += 256) {
    int r = v / GN, c = v - r * GN;
    unsigned a = lab[v];
    unsigned long long ov = ((unsigned long long)sm[v] << 32) | (unsigned)~(unsigned)v;
    bool vb[3] = { c < GN-1, r < GN-1, (!neg) && (r < GN-1) && (c < GN-1) };
    int  vo[3] = { 1, GN, GN+1 };
    #pragma unroll
    for (int d = 0; d < 3; ++d) {
      if (vb[d]) {
        unsigned w = (unsigned)(v + vo[d]);
        unsigned b = lab[w];
        if (a != b) {
          unsigned long long ow = ((unsigned long long)sm[w] << 32) | (unsigned)~w;
          unsigned long long ev = (ov < ow) ? ov : ow;   // later endpoint's ord
          unsigned lo = (a < b) ? a : b, hi = (a < b) ? b : a;
          unsigned pid = lo * 10000u + hi;
          unsigned h = (pid * 2654435761u) >> 19;        // 13-bit hash
          for (int pr2 = 0; pr2 < HSZ; ++pr2) {
            unsigned k = hkey[h];
            if (k == EMPTYK) {
              unsigned old = atomicCAS(&hkey[h], EMPTYK, pid);
              k = (old == EMPTYK) ? pid : old;
            }
            if (k == pid) { atomicMax(&hval[h], ev); break; }
            h = (h + 1) & HMASK;
          }
        }
      }
    }
  }
  __syncthreads();

  // ---- re-init lab as UF parent ----
  for (int i = tid; i < NV; i += 256) lab[i] = (unsigned short)i;
  __syncthreads();

  // ---- P3: bitonic sort (desc by hval; empties ev=0 sink to tail) ----
  for (int k = 2; k <= HSZ; k <<= 1) {
    for (int j = k >> 1; j > 0; j >>= 1) {
      for (int i = tid; i < HSZ; i += 256) {
        int l = i ^ j;
        if (l > i) {
          unsigned long long a = hval[i], b = hval[l];
          bool up = ((i & k) == 0);
          bool sw = up ? (a < b) : (a > b);     // descending overall
          if (sw) {
            hval[i] = b; hval[l] = a;
            unsigned t = hkey[i]; hkey[i] = hkey[l]; hkey[l] = t;
          }
        }
      }
      __syncthreads();
    }
  }

  // ---- P4: serial elder-rule Kruskal on lane 0 ----
  if (tid != 0) return;
  for (int e = 0; e < HSZ; ++e) {
    unsigned pid = hkey[e];
    if (pid == EMPTYK) break;
    unsigned long long ev = hval[e];
    unsigned a = pid / 10000u;
    unsigned b = pid - a * 10000u;
    // interleaved dual find with path halving
    unsigned ca = a, cb2 = b;
    while (1) {
      unsigned pa = lab[ca], pb = lab[cb2];
      bool da = (pa == ca), db = (pb == cb2);
      if (da && db) break;
      unsigned ga = lab[pa], gb = lab[pb];
      if (!da) { lab[ca] = (unsigned short)ga; ca = ga; }
      if (!db) { lab[cb2] = (unsigned short)gb; cb2 = gb; }
    }
    lab[a] = (unsigned short)ca; lab[b] = (unsigned short)cb2;   // compress
    if (ca == cb2) continue;
    unsigned long long oa = ((unsigned long long)sm[ca]  << 32) | (unsigned)~ca;
    unsigned long long ob = ((unsigned long long)sm[cb2] << 32) | (unsigned)~cb2;
    unsigned win = (oa >= ob) ? ca : cb2;
    unsigned los = (oa >= ob) ? cb2 : ca;
    float kx = unmono((unsigned)(ev >> 32));     // death value
    float kl = unmono(sm[los]);                  // defeated peak's birth value
    bars[los] = kl - kx;
    lab[los] = (unsigned short)win;
  }
}

// ---------------------------------------------------------------------------
// Kernel 3: per-problem top-20 bars, signed sum of squares -> partial[p]
// ---------------------------------------------------------------------------
__global__ __launch_bounds__(256) void topk_k(float* ws) {
  __shared__ float sb[NV];
  __shared__ float rv[256];
  __shared__ int   ri[256];
  int p = blockIdx.x;
  const float* bars = (const float*)((const char*)ws + OFF_BARS) + (size_t)p * NV;
  float* part = (float*)((char*)ws + OFF_PART);
  int tid = threadIdx.x;
  for (int i = tid; i < NV; i += 256) sb[i] = bars[i];
  __syncthreads();
  float acc = 0.f;
  for (int k = 0; k < K_TOP; ++k) {
    float mv = -1.f; int mi = NV;
    for (int i = tid; i < NV; i += 256) {
      float v = sb[i];
      if (v > mv) { mv = v; mi = i; }
    }
    rv[tid] = mv; ri[tid] = mi;
    __syncthreads();
    for (int s = 128; s > 0; s >>= 1) {
      if (tid < s) {
        if (rv[tid+s] > rv[tid] || (rv[tid+s] == rv[tid] && ri[tid+s] < ri[tid])) {
          rv[tid] = rv[tid+s]; ri[tid] = ri[tid+s];
        }
      }
      __syncthreads();
    }
    if (tid == 0) {
      float best = rv[0];
      float sgnk = (k < 5) ? -1.f : 1.f;
      acc += sgnk * best * best;
      sb[ri[0]] = -2.f;
    }
    __syncthreads();
  }
  if (tid == 0) part[p] = acc;
}

// ---------------------------------------------------------------------------
// Kernel 4: deterministic final reduction (mean over batch)
// ---------------------------------------------------------------------------
__global__ void final_k(float* ws, float* out) {
  if (threadIdx.x == 0 && blockIdx.x == 0) {
    const float* part = (const float*)((const char*)ws + OFF_PART);
    float s = 0.f;
    for (int i = 0; i < NPROB; ++i) s += part[i];
    out[0] = s / (float)NB;
  }
}

extern "C" void kernel_launch(void* const* d_in, const int* in_sizes, int n_in,
                              void* d_out, int out_size, void* d_ws, size_t ws_size,
                              hipStream_t stream) {
  const float* in = (const float*)d_in[0];
  float* ws = (float*)d_ws;
  float* out = (float*)d_out;
  hipLaunchKernelGGL(wg_weights, dim3(1), dim3(128), 0, stream, ws);
  hipLaunchKernelGGL(resize_k, dim3((NB * NV + 255) / 256), dim3(256), 0, stream, in, ws);
  hipLaunchKernelGGL(region_k, dim3(NPROB), dim3(256), 0, stream, ws);
  hipLaunchKernelGGL(topk_k, dim3(NPROB), dim3(256), 0, stream, ws);
  hipLaunchKernelGGL(final_k, dim3(1), dim3(64), 0, stream, ws, out);
}

// Round 4
// 1703.740 us; speedup vs baseline: 9.3642x; 1.7660x over previous
//
#include <hip/hip_runtime.h>
#include <math.h>

#define NB 16
#define INW 256
#define GN 100
#define NV (GN*GN)          // 10000
#define NPROB (NB*2)        // 32
#define K_TOP 20
#define HSZ 8192
#define HMASK (HSZ-1)
#define EMPTYK 0xFFFFFFFFu

// ws byte offsets
#define OFF_RES   0               // NB*NV floats = 640000
#define OFF_J0    640000
#define OFF_W     640512
#define OFF_LAB   643072         // NPROB*NV u16 = 640000
#define OFF_EDGES 1283072        // NPROB*HSZ u64 = 2097152
#define OFF_ECNT  3380224        // NPROB u32
#define OFF_BARS  3380352        // NPROB*NV f32 = 1280000
#define OFF_PART  4660352        // NPROB floats

__device__ __forceinline__ int imin(int a, int b){ return a < b ? a : b; }
__device__ __forceinline__ int imax(int a, int b){ return a > b ? a : b; }

__device__ __forceinline__ unsigned mono32(float f){
  unsigned b = __float_as_uint(f);
  return (b & 0x80000000u) ? ~b : (b | 0x80000000u);
}
__device__ __forceinline__ float unmono(unsigned m){
  unsigned b = (m & 0x80000000u) ? (m ^ 0x80000000u) : ~m;
  return __uint_as_float(b);
}

// ---------------------------------------------------------------------------
// Kernel 0: bicubic weight table
// ---------------------------------------------------------------------------
__global__ void wg_weights(float* ws) {
  int i = threadIdx.x;
  if (i >= GN) return;
  int*   j0t = (int*)((char*)ws + OFF_J0);
  float* wt  = (float*)((char*)ws + OFF_W);
  double inv = (double)INW / (double)GN;
  double sf  = ((double)i + 0.5) * inv - 0.5;
  int j0 = (int)floor(sf) - 1;
  double w[4]; double s = 0.0;
  for (int k = 0; k < 4; ++k) {
    int j = j0 + k;
    double t = fabs(sf - (double)j);
    double v;
    if (t < 1.0)      v = ((1.5*t - 2.5)*t)*t + 1.0;
    else if (t < 2.0) v = ((-0.5*t + 2.5)*t - 4.0)*t + 2.0;
    else              v = 0.0;
    if (j < 0 || j >= INW) v = 0.0;
    w[k] = v; s += v;
  }
  for (int k = 0; k < 4; ++k) wt[i*4 + k] = (float)(w[k] / s);
  j0t[i] = j0;
}

// ---------------------------------------------------------------------------
// Kernel 1: separable bicubic resize 256x256 -> 100x100
// ---------------------------------------------------------------------------
__global__ __launch_bounds__(256) void resize_k(const float* __restrict__ in, float* ws) {
  const int*   j0t = (const int*)((const char*)ws + OFF_J0);
  const float* wt  = (const float*)((const char*)ws + OFF_W);
  float* outp = (float*)((char*)ws + OFF_RES);
  int idx = blockIdx.x * 256 + threadIdx.x;
  if (idx >= NB * NV) return;
  int b = idx / NV; int rem = idx - b * NV;
  int i = rem / GN; int j = rem - i * GN;
  const float* img = in + (size_t)b * INW * INW;
  int r0 = j0t[i], c0 = j0t[j];
  float wc0 = wt[j*4+0], wc1 = wt[j*4+1], wc2 = wt[j*4+2], wc3 = wt[j*4+3];
  float acc = 0.f;
  for (int kr = 0; kr < 4; ++kr) {
    int rr = imin(imax(r0 + kr, 0), INW - 1);
    const float* row = img + rr * INW;
    int c0c = imin(imax(c0 + 0, 0), INW - 1);
    int c1c = imin(imax(c0 + 1, 0), INW - 1);
    int c2c = imin(imax(c0 + 2, 0), INW - 1);
    int c3c = imin(imax(c0 + 3, 0), INW - 1);
    float rs = wc0*row[c0c] + wc1*row[c1c] + wc2*row[c2c] + wc3*row[c3c];
    acc += wt[i*4 + kr] * rs;
  }
  outp[idx] = acc;
}

// ---------------------------------------------------------------------------
// Kernel 2: steepest-earlier-neighbor forest + direct root chase -> labels
// ---------------------------------------------------------------------------
__global__ __launch_bounds__(256) void label_k(float* ws) {
  __shared__ unsigned sm[NV];
  __shared__ unsigned short lab[NV];
  int p = blockIdx.x, samp = p >> 1, neg = p & 1, tid = threadIdx.x;
  const float* res = (const float*)((const char*)ws + OFF_RES) + samp * NV;
  unsigned short* glab = (unsigned short*)((char*)ws + OFF_LAB) + (size_t)p * NV;
  float sgn = neg ? -1.f : 1.f;
  for (int i = tid; i < NV; i += 256) sm[i] = mono32(sgn * res[i]);
  __syncthreads();
  const int nd = neg ? 4 : 6;
  for (int v = tid; v < NV; v += 256) {
    int r = v / GN, c = v - r * GN;
    unsigned long long best = ((unsigned long long)sm[v] << 32) | (unsigned)~(unsigned)v;
    unsigned bi = (unsigned)v;
    bool cb[6] = { c < GN-1, c > 0, r < GN-1, r > 0,
                   (r < GN-1) && (c < GN-1), (r > 0) && (c > 0) };
    int  off[6] = { 1, -1, GN, -GN, GN+1, -(GN+1) };
    #pragma unroll
    for (int d = 0; d < 6; ++d) {
      if (d < nd && cb[d]) {
        unsigned y = (unsigned)(v + off[d]);
        unsigned long long o = ((unsigned long long)sm[y] << 32) | (unsigned)~y;
        if (o > best) { best = o; bi = y; }
      }
    }
    lab[v] = (unsigned short)bi;
  }
  __syncthreads();
  // direct chase with compression (concurrent writes are ancestor-safe)
  for (int v = tid; v < NV; v += 256) {
    unsigned r = lab[v];
    while (1) { unsigned n = lab[r]; if (n == r) break; r = n; }
    lab[v] = (unsigned short)r;
    glab[v] = (unsigned short)r;
  }
}

// ---------------------------------------------------------------------------
// Kernel 3: boundary-edge hashing (u32 events) + compaction to dense edges
// ---------------------------------------------------------------------------
__global__ __launch_bounds__(256) void hash_k(float* ws) {
  __shared__ unsigned sm[NV];
  __shared__ unsigned hkey[HSZ];
  __shared__ unsigned hval[HSZ];
  __shared__ unsigned short lab[NV];
  __shared__ unsigned cnt[256];
  int p = blockIdx.x, samp = p >> 1, neg = p & 1, tid = threadIdx.x;
  const float* res = (const float*)((const char*)ws + OFF_RES) + samp * NV;
  const unsigned short* glab = (const unsigned short*)((const char*)ws + OFF_LAB) + (size_t)p * NV;
  unsigned long long* gedges = (unsigned long long*)((char*)ws + OFF_EDGES) + (size_t)p * HSZ;
  unsigned* ecnt = (unsigned*)((char*)ws + OFF_ECNT);
  float sgn = neg ? -1.f : 1.f;
  for (int i = tid; i < NV; i += 256) { sm[i] = mono32(sgn * res[i]); lab[i] = glab[i]; }
  for (int s = tid; s < HSZ; s += 256) { hkey[s] = EMPTYK; hval[s] = 0u; }
  __syncthreads();
  for (int v = tid; v < NV; v += 256) {
    int r = v / GN, c = v - r * GN;
    unsigned a = lab[v];
    unsigned sv = sm[v];
    bool vb[3] = { c < GN-1, r < GN-1, (!neg) && (r < GN-1) && (c < GN-1) };
    int  vo[3] = { 1, GN, GN+1 };
    #pragma unroll
    for (int d = 0; d < 3; ++d) {
      if (vb[d]) {
        unsigned w = (unsigned)(v + vo[d]);
        unsigned b = lab[w];
        if (a != b) {
          unsigned sw = sm[w];
          unsigned ev = (sv < sw) ? sv : sw;             // death = later endpoint's value
          unsigned lo = (a < b) ? a : b, hi = (a < b) ? b : a;
          unsigned pid = lo * 10000u + hi;
          unsigned h = (pid * 2654435761u) >> 19;
          for (int pr2 = 0; pr2 < HSZ; ++pr2) {
            unsigned k = hkey[h];
            if (k == EMPTYK) {
              unsigned old = atomicCAS(&hkey[h], EMPTYK, pid);
              k = (old == EMPTYK) ? pid : old;
            }
            if (k == pid) { atomicMax(&hval[h], ev); break; }
            h = (h + 1) & HMASK;
          }
        }
      }
    }
  }
  __syncthreads();
  // compact: count per-thread, Hillis-Steele scan, write dense
  unsigned my = 0;
  for (int s = tid; s < HSZ; s += 256) if (hkey[s] != EMPTYK) ++my;
  cnt[tid] = my;
  __syncthreads();
  for (int off = 1; off < 256; off <<= 1) {
    unsigned t = (tid >= off) ? cnt[tid - off] : 0u;
    __syncthreads();
    cnt[tid] += t;
    __syncthreads();
  }
  unsigned base = cnt[tid] - my;
  for (int s = tid; s < HSZ; s += 256) {
    if (hkey[s] != EMPTYK) {
      gedges[base++] = ((unsigned long long)hval[s] << 32) | hkey[s];
    }
  }
  if (tid == 255) ecnt[p] = cnt[255];
}

// ---------------------------------------------------------------------------
// Kernel 4: bitonic sort (desc) of packed u64 edges, dynamic size
// ---------------------------------------------------------------------------
__global__ __launch_bounds__(256) void sort_k(float* ws) {
  __shared__ unsigned long long items[HSZ];
  int p = blockIdx.x, tid = threadIdx.x;
  unsigned long long* gedges = (unsigned long long*)((char*)ws + OFF_EDGES) + (size_t)p * HSZ;
  const unsigned* ecnt = (const unsigned*)((const char*)ws + OFF_ECNT);
  unsigned E = ecnt[p];
  if (E > HSZ) E = HSZ;
  int S = 2; while (S < (int)E) S <<= 1;
  for (int i = tid; i < S; i += 256) items[i] = (i < (int)E) ? gedges[i] : 0ull;
  __syncthreads();
  for (int k = 2; k <= S; k <<= 1) {
    for (int j = k >> 1; j > 0; j >>= 1) {
      for (int i = tid; i < S; i += 256) {
        int l = i ^ j;
        if (l > i) {
          unsigned long long a = items[i], b = items[l];
          bool up = ((i & k) == 0);
          if (up ? (a < b) : (a > b)) { items[i] = b; items[l] = a; }
        }
      }
      __syncthreads();
    }
  }
  for (int i = tid; i < (int)E; i += 256) gedges[i] = items[i];
}

// ---------------------------------------------------------------------------
// Kernel 5: elder-rule Kruskal with wave-parallel speculative finds
// ---------------------------------------------------------------------------
__global__ __launch_bounds__(256) void kruskal_k(float* ws) {
  __shared__ unsigned sm[NV];
  __shared__ unsigned long long items[HSZ];
  __shared__ unsigned short par[NV];
  __shared__ uint4 stag[65];
  int p = blockIdx.x, samp = p >> 1, neg = p & 1, tid = threadIdx.x;
  const float* res = (const float*)((const char*)ws + OFF_RES) + samp * NV;
  const unsigned long long* gedges = (const unsigned long long*)((const char*)ws + OFF_EDGES) + (size_t)p * HSZ;
  const unsigned* ecnt = (const unsigned*)((const char*)ws + OFF_ECNT);
  float* bars = (float*)((char*)ws + OFF_BARS) + (size_t)p * NV;
  float sgn = neg ? -1.f : 1.f;
  unsigned E = ecnt[p];
  if (E > HSZ) E = HSZ;
  for (int i = tid; i < NV; i += 256) {
    sm[i] = mono32(sgn * res[i]);
    par[i] = (unsigned short)i;
    bars[i] = 0.f;
  }
  for (int i = tid; i < (int)E; i += 256) items[i] = gedges[i];
  __syncthreads();
  if (tid >= 64) return;
  const int lane = tid;
  for (unsigned chunk = 0; chunk < E; chunk += 64) {
    unsigned rem = E - chunk; if (rem > 64) rem = 64;
    // speculative parallel finds (find-only phase: halving writes are safe)
    unsigned ra = 0, rb = 0, smd = 0;
    if (lane < (int)rem) {
      unsigned long long it = items[chunk + lane];
      smd = (unsigned)(it >> 32);
      unsigned pid = (unsigned)it;
      unsigned a = pid / 10000u;
      unsigned b = pid - a * 10000u;
      unsigned cur = a, pp = par[cur];
      while (pp != cur) { unsigned gp = par[pp]; par[cur] = (unsigned short)gp; cur = gp; pp = par[cur]; }
      ra = cur;
      cur = b; pp = par[cur];
      while (pp != cur) { unsigned gp = par[pp]; par[cur] = (unsigned short)gp; cur = gp; pp = par[cur]; }
      rb = cur;
    }
    uint4 h; h.x = ra; h.y = rb; h.z = smd; h.w = 0;
    stag[lane] = h;
    __asm__ volatile("s_waitcnt lgkmcnt(0)" ::: "memory");
    __builtin_amdgcn_wave_barrier();
    if (lane == 0) {
      uint4 cur = stag[0];
      for (int t = 0; t < (int)rem; ++t) {
        uint4 nxt = stag[t + 1];            // prefetch (slot 64 exists; garbage unused)
        unsigned ca = cur.x, pp = par[ca];
        while (pp != ca) { unsigned gp = par[pp]; par[ca] = (unsigned short)gp; ca = gp; pp = par[ca]; }
        unsigned cb = cur.y; pp = par[cb];
        while (pp != cb) { unsigned gp = par[pp]; par[cb] = (unsigned short)gp; cb = gp; pp = par[cb]; }
        if (ca != cb) {
          unsigned long long oa = ((unsigned long long)sm[ca] << 32) | (unsigned)~ca;
          unsigned long long ob = ((unsigned long long)sm[cb] << 32) | (unsigned)~cb;
          unsigned win = (oa >= ob) ? ca : cb;
          unsigned los = (oa >= ob) ? cb : ca;
          bars[los] = unmono(sm[los]) - unmono(cur.z);
          par[los] = (unsigned short)win;
        }
        cur = nxt;
      }
    }
    __asm__ volatile("s_waitcnt lgkmcnt(0)" ::: "memory");
    __builtin_amdgcn_wave_barrier();
  }
}

// ---------------------------------------------------------------------------
// Kernel 6: per-problem top-20 bars, signed sum of squares -> partial[p]
// ---------------------------------------------------------------------------
__global__ __launch_bounds__(256) void topk_k(float* ws) {
  __shared__ float sb[NV];
  __shared__ float rv[256];
  __shared__ int   ri[256];
  int p = blockIdx.x;
  const float* bars = (const float*)((const char*)ws + OFF_BARS) + (size_t)p * NV;
  float* part = (float*)((char*)ws + OFF_PART);
  int tid = threadIdx.x;
  for (int i = tid; i < NV; i += 256) sb[i] = bars[i];
  __syncthreads();
  float acc = 0.f;
  for (int k = 0; k < K_TOP; ++k) {
    float mv = -1.f; int mi = NV;
    for (int i = tid; i < NV; i += 256) {
      float v = sb[i];
      if (v > mv) { mv = v; mi = i; }
    }
    rv[tid] = mv; ri[tid] = mi;
    __syncthreads();
    for (int s = 128; s > 0; s >>= 1) {
      if (tid < s) {
        if (rv[tid+s] > rv[tid] || (rv[tid+s] == rv[tid] && ri[tid+s] < ri[tid])) {
          rv[tid] = rv[tid+s]; ri[tid] = ri[tid+s];
        }
      }
      __syncthreads();
    }
    if (tid == 0) {
      float best = rv[0];
      float sgnk = (k < 5) ? -1.f : 1.f;
      acc += sgnk * best * best;
      sb[ri[0]] = -2.f;
    }
    __syncthreads();
  }
  if (tid == 0) part[p] = acc;
}

// ---------------------------------------------------------------------------
// Kernel 7: deterministic final reduction (mean over batch)
// ---------------------------------------------------------------------------
__global__ void final_k(float* ws, float* out) {
  if (threadIdx.x == 0 && blockIdx.x == 0) {
    const float* part = (const float*)((const char*)ws + OFF_PART);
    float s = 0.f;
    for (int i = 0; i < NPROB; ++i) s += part[i];
    out[0] = s / (float)NB;
  }
}

extern "C" void kernel_launch(void* const* d_in, const int* in_sizes, int n_in,
                              void* d_out, int out_size, void* d_ws, size_t ws_size,
                              hipStream_t stream) {
  const float* in = (const float*)d_in[0];
  float* ws = (float*)d_ws;
  float* out = (float*)d_out;
  hipLaunchKernelGGL(wg_weights, dim3(1), dim3(128), 0, stream, ws);
  hipLaunchKernelGGL(resize_k, dim3((NB * NV + 255) / 256), dim3(256), 0, stream, in, ws);
  hipLaunchKernelGGL(label_k, dim3(NPROB), dim3(256), 0, stream, ws);
  hipLaunchKernelGGL(hash_k, dim3(NPROB), dim3(256), 0, stream, ws);
  hipLaunchKernelGGL(sort_k, dim3(NPROB), dim3(256), 0, stream, ws);
  hipLaunchKernelGGL(kruskal_k, dim3(NPROB), dim3(256), 0, stream, ws);
  hipLaunchKernelGGL(topk_k, dim3(NPROB), dim3(256), 0, stream, ws);
  hipLaunchKernelGGL(final_k, dim3(1), dim3(64), 0, stream, ws, out);
}

// Round 5
// 889.906 us; speedup vs baseline: 17.9279x; 1.9145x over previous
//
#include <hip/hip_runtime.h>
#include <math.h>

#define NB 16
#define INW 256
#define GN 100
#define NV (GN*GN)          // 10000
#define NPROB (NB*2)        // 32
#define K_TOP 20
#define HSZ 8192
#define HMASK (HSZ-1)
#define EMPTYK 0xFFFFFFFFu
#define KB 16               // value-range buckets per problem
#define RCAP 6144           // max regions per problem

// ws byte offsets
#define OFF_RES   0               // NB*NV f32 = 640000
#define OFF_J0    640000
#define OFF_W     640512
#define OFF_LAB   643072          // NPROB*NV u16 = 640000
#define OFF_DENSE 1283072         // NPROB*NV u16 = 640000
#define OFF_D2O   1923072         // NPROB*RCAP u64 = 1572864
#define OFF_EDGES 3495936         // NPROB*HSZ u64 = 2097152
#define OFF_ECNT  5593088         // NPROB u32
#define OFF_RCNT  5593216         // NPROB u32
#define OFF_BARS  5593344         // NPROB*NV f32 = 1280000
#define OFF_PART  6873344         // NPROB f32

__device__ __forceinline__ int imin(int a, int b){ return a < b ? a : b; }
__device__ __forceinline__ int imax(int a, int b){ return a > b ? a : b; }

__device__ __forceinline__ unsigned mono32(float f){
  unsigned b = __float_as_uint(f);
  return (b & 0x80000000u) ? ~b : (b | 0x80000000u);
}
__device__ __forceinline__ float unmono(unsigned m){
  unsigned b = (m & 0x80000000u) ? (m ^ 0x80000000u) : ~m;
  return __uint_as_float(b);
}

// ---------------------------------------------------------------------------
// Kernel 0: bicubic weight table
// ---------------------------------------------------------------------------
__global__ void wg_weights(float* ws) {
  int i = threadIdx.x;
  if (i >= GN) return;
  int*   j0t = (int*)((char*)ws + OFF_J0);
  float* wt  = (float*)((char*)ws + OFF_W);
  double inv = (double)INW / (double)GN;
  double sf  = ((double)i + 0.5) * inv - 0.5;
  int j0 = (int)floor(sf) - 1;
  double w[4]; double s = 0.0;
  for (int k = 0; k < 4; ++k) {
    int j = j0 + k;
    double t = fabs(sf - (double)j);
    double v;
    if (t < 1.0)      v = ((1.5*t - 2.5)*t)*t + 1.0;
    else if (t < 2.0) v = ((-0.5*t + 2.5)*t - 4.0)*t + 2.0;
    else              v = 0.0;
    if (j < 0 || j >= INW) v = 0.0;
    w[k] = v; s += v;
  }
  for (int k = 0; k < 4; ++k) wt[i*4 + k] = (float)(w[k] / s);
  j0t[i] = j0;
}

// ---------------------------------------------------------------------------
// Kernel 1: separable bicubic resize 256x256 -> 100x100
// ---------------------------------------------------------------------------
__global__ __launch_bounds__(256) void resize_k(const float* __restrict__ in, float* ws) {
  const int*   j0t = (const int*)((const char*)ws + OFF_J0);
  const float* wt  = (const float*)((const char*)ws + OFF_W);
  float* outp = (float*)((char*)ws + OFF_RES);
  int idx = blockIdx.x * 256 + threadIdx.x;
  if (idx >= NB * NV) return;
  int b = idx / NV; int rem = idx - b * NV;
  int i = rem / GN; int j = rem - i * GN;
  const float* img = in + (size_t)b * INW * INW;
  int r0 = j0t[i], c0 = j0t[j];
  float wc0 = wt[j*4+0], wc1 = wt[j*4+1], wc2 = wt[j*4+2], wc3 = wt[j*4+3];
  float acc = 0.f;
  for (int kr = 0; kr < 4; ++kr) {
    int rr = imin(imax(r0 + kr, 0), INW - 1);
    const float* row = img + rr * INW;
    int c0c = imin(imax(c0 + 0, 0), INW - 1);
    int c1c = imin(imax(c0 + 1, 0), INW - 1);
    int c2c = imin(imax(c0 + 2, 0), INW - 1);
    int c3c = imin(imax(c0 + 3, 0), INW - 1);
    float rs = wc0*row[c0c] + wc1*row[c1c] + wc2*row[c2c] + wc3*row[c3c];
    acc += wt[i*4 + kr] * rs;
  }
  outp[idx] = acc;
}

// ---------------------------------------------------------------------------
// Kernel 2: steepest-earlier-neighbor forest -> watershed labels (+ zero bars)
// ---------------------------------------------------------------------------
__global__ __launch_bounds__(256) void label_k(float* ws) {
  __shared__ unsigned sm[NV];
  __shared__ unsigned short lab[NV];
  int p = blockIdx.x, samp = p >> 1, neg = p & 1, tid = threadIdx.x;
  const float* res = (const float*)((const char*)ws + OFF_RES) + samp * NV;
  unsigned short* glab = (unsigned short*)((char*)ws + OFF_LAB) + (size_t)p * NV;
  float* bars = (float*)((char*)ws + OFF_BARS) + (size_t)p * NV;
  float sgn = neg ? -1.f : 1.f;
  for (int i = tid; i < NV; i += 256) { sm[i] = mono32(sgn * res[i]); bars[i] = 0.f; }
  __syncthreads();
  const int nd = neg ? 4 : 6;
  for (int v = tid; v < NV; v += 256) {
    int r = v / GN, c = v - r * GN;
    unsigned long long best = ((unsigned long long)sm[v] << 32) | (unsigned)~(unsigned)v;
    unsigned bi = (unsigned)v;
    bool cb[6] = { c < GN-1, c > 0, r < GN-1, r > 0,
                   (r < GN-1) && (c < GN-1), (r > 0) && (c > 0) };
    int  off[6] = { 1, -1, GN, -GN, GN+1, -(GN+1) };
    #pragma unroll
    for (int d = 0; d < 6; ++d) {
      if (d < nd && cb[d]) {
        unsigned y = (unsigned)(v + off[d]);
        unsigned long long o = ((unsigned long long)sm[y] << 32) | (unsigned)~y;
        if (o > best) { best = o; bi = y; }
      }
    }
    lab[v] = (unsigned short)bi;
  }
  __syncthreads();
  for (int v = tid; v < NV; v += 256) {
    unsigned r = lab[v];
    while (1) { unsigned n = lab[r]; if (n == r) break; r = n; }
    lab[v] = (unsigned short)r;
    glab[v] = (unsigned short)r;
  }
}

// ---------------------------------------------------------------------------
// Kernel 3: rename region roots to dense ids + peak-ord table
// ---------------------------------------------------------------------------
__global__ __launch_bounds__(256) void rename_k(float* ws) {
  __shared__ unsigned cnt[256];
  int p = blockIdx.x, samp = p >> 1, neg = p & 1, tid = threadIdx.x;
  const float* res = (const float*)((const char*)ws + OFF_RES) + samp * NV;
  const unsigned short* glab = (const unsigned short*)((const char*)ws + OFF_LAB) + (size_t)p * NV;
  unsigned short* dense = (unsigned short*)((char*)ws + OFF_DENSE) + (size_t)p * NV;
  unsigned long long* d2o = (unsigned long long*)((char*)ws + OFF_D2O) + (size_t)p * RCAP;
  unsigned* rcnt = (unsigned*)((char*)ws + OFF_RCNT);
  float sgn = neg ? -1.f : 1.f;
  unsigned my = 0;
  for (int v = tid; v < NV; v += 256) if (glab[v] == (unsigned short)v) ++my;
  cnt[tid] = my;
  __syncthreads();
  for (int off = 1; off < 256; off <<= 1) {
    unsigned t = (tid >= off) ? cnt[tid - off] : 0u;
    __syncthreads();
    cnt[tid] += t;
    __syncthreads();
  }
  unsigned base = cnt[tid] - my;
  for (int v = tid; v < NV; v += 256) {
    if (glab[v] == (unsigned short)v) {
      if (base < RCAP) {
        dense[v] = (unsigned short)base;
        d2o[base] = ((unsigned long long)mono32(sgn * res[v]) << 32) | (unsigned)~(unsigned)v;
      }
      ++base;
    }
  }
  if (tid == 255) rcnt[p] = cnt[255];
}

// ---------------------------------------------------------------------------
// Kernel 4: boundary-edge hashing (dense pids, u32 events) + compaction
// ---------------------------------------------------------------------------
__global__ __launch_bounds__(256) void hash_k(float* ws) {
  __shared__ unsigned sm[NV];
  __shared__ unsigned hkey[HSZ];
  __shared__ unsigned hval[HSZ];
  __shared__ unsigned short lab[NV];
  __shared__ unsigned short dn[NV];
  __shared__ unsigned cnt[256];
  int p = blockIdx.x, samp = p >> 1, neg = p & 1, tid = threadIdx.x;
  const float* res = (const float*)((const char*)ws + OFF_RES) + samp * NV;
  const unsigned short* glab = (const unsigned short*)((const char*)ws + OFF_LAB) + (size_t)p * NV;
  const unsigned short* gdense = (const unsigned short*)((const char*)ws + OFF_DENSE) + (size_t)p * NV;
  unsigned long long* gedges = (unsigned long long*)((char*)ws + OFF_EDGES) + (size_t)p * HSZ;
  unsigned* ecnt = (unsigned*)((char*)ws + OFF_ECNT);
  float sgn = neg ? -1.f : 1.f;
  for (int i = tid; i < NV; i += 256) {
    sm[i] = mono32(sgn * res[i]); lab[i] = glab[i]; dn[i] = gdense[i];
  }
  for (int s = tid; s < HSZ; s += 256) { hkey[s] = EMPTYK; hval[s] = 0u; }
  __syncthreads();
  for (int v = tid; v < NV; v += 256) {
    int r = v / GN, c = v - r * GN;
    unsigned a = lab[v];
    unsigned sv = sm[v];
    bool vb[3] = { c < GN-1, r < GN-1, (!neg) && (r < GN-1) && (c < GN-1) };
    int  vo[3] = { 1, GN, GN+1 };
    #pragma unroll
    for (int d = 0; d < 3; ++d) {
      if (vb[d]) {
        unsigned w = (unsigned)(v + vo[d]);
        unsigned b = lab[w];
        if (a != b) {
          unsigned sw = sm[w];
          unsigned ev = (sv < sw) ? sv : sw;
          unsigned da = dn[a], db = dn[b];
          unsigned dlo = (da < db) ? da : db, dhi = (da < db) ? db : da;
          unsigned pid = (dlo << 16) | dhi;
          unsigned h = (pid * 2654435761u) >> 19;
          for (int pr2 = 0; pr2 < HSZ; ++pr2) {
            unsigned k = hkey[h];
            if (k == EMPTYK) {
              unsigned old = atomicCAS(&hkey[h], EMPTYK, pid);
              k = (old == EMPTYK) ? pid : old;
            }
            if (k == pid) { atomicMax(&hval[h], ev); break; }
            h = (h + 1) & HMASK;
          }
        }
      }
    }
  }
  __syncthreads();
  unsigned my = 0;
  for (int s = tid; s < HSZ; s += 256) if (hkey[s] != EMPTYK) ++my;
  cnt[tid] = my;
  __syncthreads();
  for (int off = 1; off < 256; off <<= 1) {
    unsigned t = (tid >= off) ? cnt[tid - off] : 0u;
    __syncthreads();
    cnt[tid] += t;
    __syncthreads();
  }
  unsigned base = cnt[tid] - my;
  for (int s = tid; s < HSZ; s += 256) {
    if (hkey[s] != EMPTYK) {
      gedges[base++] = ((unsigned long long)hval[s] << 32) | hkey[s];
    }
  }
  if (tid == 255) ecnt[p] = cnt[255];
}

// ---------------------------------------------------------------------------
// Kernel 5: bitonic sort (desc) of packed u64 edges
// ---------------------------------------------------------------------------
__global__ __launch_bounds__(256) void sort_k(float* ws) {
  __shared__ unsigned long long items[HSZ];
  int p = blockIdx.x, tid = threadIdx.x;
  unsigned long long* gedges = (unsigned long long*)((char*)ws + OFF_EDGES) + (size_t)p * HSZ;
  const unsigned* ecnt = (const unsigned*)((const char*)ws + OFF_ECNT);
  unsigned E = ecnt[p];
  if (E > HSZ) E = HSZ;
  int S = 2; while (S < (int)E) S <<= 1;
  for (int i = tid; i < S; i += 256) items[i] = (i < (int)E) ? gedges[i] : 0ull;
  __syncthreads();
  for (int k = 2; k <= S; k <<= 1) {
    for (int j = k >> 1; j > 0; j >>= 1) {
      for (int i = tid; i < S; i += 256) {
        int l = i ^ j;
        if (l > i) {
          unsigned long long a = items[i], b = items[l];
          bool up = ((i & k) == 0);
          if (up ? (a < b) : (a > b)) { items[i] = b; items[l] = a; }
        }
      }
      __syncthreads();
    }
  }
  for (int i = tid; i < (int)E; i += 256) gedges[i] = items[i];
}

// ---------------------------------------------------------------------------
// Kernel 6: bucketed elder-rule Kruskal. One block per (problem, bucket).
//  start state = components of prefix edges (parallel min-hook CC)
//  + per-component peak ord (parallel atomicMax)
//  + serial Kruskal over this bucket's ~E/KB edges only.
// ---------------------------------------------------------------------------
__global__ __launch_bounds__(256) void kruskal_bucket_k(float* ws) {
  __shared__ unsigned long long items[HSZ + 1];
  __shared__ unsigned par[RCAP];
  __shared__ unsigned long long peak[RCAP];
  __shared__ int flag;
  int p = blockIdx.x / KB, bk = blockIdx.x % KB, tid = threadIdx.x;
  const unsigned long long* gedges = (const unsigned long long*)((const char*)ws + OFF_EDGES) + (size_t)p * HSZ;
  const unsigned long long* d2o = (const unsigned long long*)((const char*)ws + OFF_D2O) + (size_t)p * RCAP;
  const unsigned* ecnt = (const unsigned*)((const char*)ws + OFF_ECNT);
  const unsigned* rcnt = (const unsigned*)((const char*)ws + OFF_RCNT);
  float* bars = (float*)((char*)ws + OFF_BARS) + (size_t)p * NV;
  unsigned E = ecnt[p]; if (E > HSZ) E = HSZ;
  unsigned R = rcnt[p]; if (R > RCAP) R = RCAP;
  unsigned chunk = (E + KB - 1) / KB;
  unsigned my_lo = bk * chunk; if (my_lo > E) my_lo = E;
  unsigned my_hi = my_lo + chunk; if (my_hi > E) my_hi = E;
  for (unsigned i = tid; i < my_hi; i += 256) items[i] = gedges[i];
  for (unsigned d = tid; d < R; d += 256) { par[d] = d; peak[d] = d2o[d]; }
  __syncthreads();
  // ---- parallel CC over prefix edges [0, my_lo) ----
  while (1) {
    if (tid == 0) flag = 0;
    __syncthreads();
    for (unsigned e = tid; e < my_lo; e += 256) {
      unsigned pid = (unsigned)items[e];
      unsigned a = pid >> 16, b = pid & 0xffffu;
      unsigned ra = a; while (par[ra] != ra) ra = par[ra];
      unsigned rb = b; while (par[rb] != rb) rb = par[rb];
      if (ra != rb) {
        unsigned mn = (ra < rb) ? ra : rb, mx = (ra < rb) ? rb : ra;
        atomicMin(&par[mx], mn);
        flag = 1;
      }
    }
    __syncthreads();
    if (!flag) break;
    for (unsigned d = tid; d < R; d += 256) {
      unsigned r = d; while (par[r] != r) r = par[r];
      par[d] = r;
    }
    __syncthreads();
  }
  // ---- component peak ords (all pars are fully compressed now) ----
  for (unsigned d = tid; d < R; d += 256) {
    unsigned r = par[d];
    if (r != d) atomicMax(&peak[r], peak[d]);
  }
  __syncthreads();
  // ---- serial Kruskal over [my_lo, my_hi) ----
  if (tid != 0) return;
  unsigned long long it = items[my_lo];     // items[E] slot exists (HSZ+1)
  for (unsigned e = my_lo; e < my_hi; ++e) {
    unsigned long long nx = items[e + 1];   // prefetch
    unsigned ev = (unsigned)(it >> 32);
    unsigned pid = (unsigned)it;
    unsigned ca = pid >> 16, cb = pid & 0xffffu;
    while (1) {                              // interleaved dual find, path halving
      unsigned pa = par[ca], pb = par[cb];
      bool da = (pa == ca), db = (pb == cb);
      if (da && db) break;
      unsigned ga = par[pa], gb = par[pb];
      if (!da) { par[ca] = ga; ca = ga; }
      if (!db) { par[cb] = gb; cb = gb; }
    }
    if (ca != cb) {
      unsigned long long pa = peak[ca], pb = peak[cb];
      unsigned win = (pa >= pb) ? ca : cb;
      unsigned los = (pa >= pb) ? cb : ca;
      unsigned long long lord = (pa >= pb) ? pb : pa;
      unsigned losid = ~(unsigned)lord;     // original vertex id of defeated peak
      bars[losid] = unmono((unsigned)(lord >> 32)) - unmono(ev);
      par[los] = win;
    }
    it = nx;
  }
}

// ---------------------------------------------------------------------------
// Kernel 7: per-problem top-20 bars, signed sum of squares -> partial[p]
// ---------------------------------------------------------------------------
__global__ __launch_bounds__(256) void topk_k(float* ws) {
  __shared__ float sb[NV];
  __shared__ float rv[256];
  __shared__ int   ri[256];
  int p = blockIdx.x;
  const float* bars = (const float*)((const char*)ws + OFF_BARS) + (size_t)p * NV;
  float* part = (float*)((char*)ws + OFF_PART);
  int tid = threadIdx.x;
  for (int i = tid; i < NV; i += 256) sb[i] = bars[i];
  __syncthreads();
  float acc = 0.f;
  for (int k = 0; k < K_TOP; ++k) {
    float mv = -1.f; int mi = NV;
    for (int i = tid; i < NV; i += 256) {
      float v = sb[i];
      if (v > mv) { mv = v; mi = i; }
    }
    rv[tid] = mv; ri[tid] = mi;
    __syncthreads();
    for (int s = 128; s > 0; s >>= 1) {
      if (tid < s) {
        if (rv[tid+s] > rv[tid] || (rv[tid+s] == rv[tid] && ri[tid+s] < ri[tid])) {
          rv[tid] = rv[tid+s]; ri[tid] = ri[tid+s];
        }
      }
      __syncthreads();
    }
    if (tid == 0) {
      float best = rv[0];
      float sgnk = (k < 5) ? -1.f : 1.f;
      acc += sgnk * best * best;
      sb[ri[0]] = -2.f;
    }
    __syncthreads();
  }
  if (tid == 0) part[p] = acc;
}

// ---------------------------------------------------------------------------
// Kernel 8: deterministic final reduction (mean over batch)
// ---------------------------------------------------------------------------
__global__ void final_k(float* ws, float* out) {
  if (threadIdx.x == 0 && blockIdx.x == 0) {
    const float* part = (const float*)((const char*)ws + OFF_PART);
    float s = 0.f;
    for (int i = 0; i < NPROB; ++i) s += part[i];
    out[0] = s / (float)NB;
  }
}

extern "C" void kernel_launch(void* const* d_in, const int* in_sizes, int n_in,
                              void* d_out, int out_size, void* d_ws, size_t ws_size,
                              hipStream_t stream) {
  const float* in = (const float*)d_in[0];
  float* ws = (float*)d_ws;
  float* out = (float*)d_out;
  hipLaunchKernelGGL(wg_weights, dim3(1), dim3(128), 0, stream, ws);
  hipLaunchKernelGGL(resize_k, dim3((NB * NV + 255) / 256), dim3(256), 0, stream, in, ws);
  hipLaunchKernelGGL(label_k, dim3(NPROB), dim3(256), 0, stream, ws);
  hipLaunchKernelGGL(rename_k, dim3(NPROB), dim3(256), 0, stream, ws);
  hipLaunchKernelGGL(hash_k, dim3(NPROB), dim3(256), 0, stream, ws);
  hipLaunchKernelGGL(sort_k, dim3(NPROB), dim3(256), 0, stream, ws);
  hipLaunchKernelGGL(kruskal_bucket_k, dim3(NPROB * KB), dim3(256), 0, stream, ws);
  hipLaunchKernelGGL(topk_k, dim3(NPROB), dim3(256), 0, stream, ws);
  hipLaunchKernelGGL(final_k, dim3(1), dim3(64), 0, stream, ws, out);
}